// Round 1
// baseline (356.208 us; speedup 1.0000x reference)
//
#include <hip/hip_runtime.h>
#include <hip/hip_bf16.h>
#include <math.h>

#define EPS 1e-6f

constexpr int D  = 512;
constexpr int BM = 128;
constexpr int BN = 128;
constexpr int BK = 32;

typedef __attribute__((ext_vector_type(8))) short  short8;
typedef __attribute__((ext_vector_type(4))) float  floatx4;

// ---------------- prep: fp32 -> bf16 + per-row ||x||^(-1/2) ----------------
// One block per row (D=512, 256 threads, float2 per thread).
__global__ __launch_bounds__(256) void prep_kernel(
    const float* __restrict__ src, __hip_bfloat16* __restrict__ dst,
    float* __restrict__ isn) {
  const int row = blockIdx.x;
  const int t   = threadIdx.x;
  const float2 v = ((const float2*)(src + (size_t)row * D))[t];
  if (dst != nullptr) {
    __hip_bfloat16* drow = dst + (size_t)row * D;
    drow[2 * t]     = __float2bfloat16(v.x);
    drow[2 * t + 1] = __float2bfloat16(v.y);
  }
  float ss = v.x * v.x + v.y * v.y;
  #pragma unroll
  for (int o = 32; o > 0; o >>= 1) ss += __shfl_down(ss, o);
  __shared__ float red[4];
  if ((t & 63) == 0) red[t >> 6] = ss;
  __syncthreads();
  if (t == 0) {
    const float tot = red[0] + red[1] + red[2] + red[3];
    const float n1  = sqrtf(tot);        // ||row||
    isn[row] = 1.0f / sqrtf(n1);         // ||row||^(-1/2); 1/(sqrt(n1*n2)+eps) ~= isnA*isnB
  }
}

// ---------------- main bf16 MFMA GEMM, C = A * B^T, m97 structure ----------
// 128x128 block tile, BK=32, 4 waves in 2x2 (64x64 each), 4x4 of 16x16x32 MFMA.
__global__ __launch_bounds__(256) void gemm_bt_kernel(
    const __hip_bfloat16* __restrict__ A, const __hip_bfloat16* __restrict__ B,
    const float* __restrict__ ia, const float* __restrict__ ib,
    const int* __restrict__ nrmflag, float* __restrict__ C,
    int N, int M) {
  __shared__ __align__(16) __hip_bfloat16 sA[BM * BK];   // 8 KiB, row-major [128][32]
  __shared__ __align__(16) __hip_bfloat16 sB[BN * BK];   // 8 KiB

  const int t    = threadIdx.x;
  const int w    = t >> 6;
  const int lane = t & 63;
  const int wm   = w & 1;        // wave row (0..1)
  const int wn   = w >> 1;       // wave col (0..1)

  const size_t rowA0 = (size_t)blockIdx.x * BM;
  const size_t rowB0 = (size_t)blockIdx.y * BN;

  floatx4 acc[4][4];
  #pragma unroll
  for (int i = 0; i < 4; ++i)
    #pragma unroll
    for (int j = 0; j < 4; ++j) acc[i][j] = (floatx4){0.f, 0.f, 0.f, 0.f};

  // global_load_lds staging geometry: one wave instr moves 1 KiB = 16 tile rows.
  // lane -> row lane/4 within chunk, 16B piece (lane%4) within the 64B row.
  const int ldRow = lane >> 2;           // 0..15
  const int ldCol = (lane & 3) * 8;      // bf16 elements: 0,8,16,24
  // fragment read geometry (A[m=lane&15][k=quad*8+j], B same by B^T symmetry)
  const int fr = lane & 15;
  const int fq = (lane >> 4) * 8;

  const __hip_bfloat16* gA0 = A + (rowA0 + (size_t)ldRow) * D + ldCol;
  const __hip_bfloat16* gB0 = B + (rowB0 + (size_t)ldRow) * D + ldCol;

  for (int k0 = 0; k0 < D; k0 += BK) {
    #pragma unroll
    for (int j = 0; j < 2; ++j) {
      const int c = w * 2 + j;           // chunk 0..7, wave-uniform
      __builtin_amdgcn_global_load_lds(
          (const __attribute__((address_space(1))) void*)(gA0 + (size_t)(c * 16) * D + k0),
          (__attribute__((address_space(3))) void*)(sA + c * 512), 16, 0, 0);
      __builtin_amdgcn_global_load_lds(
          (const __attribute__((address_space(1))) void*)(gB0 + (size_t)(c * 16) * D + k0),
          (__attribute__((address_space(3))) void*)(sB + c * 512), 16, 0, 0);
    }
    __syncthreads();   // drains vmcnt(0): LDS tiles visible

    short8 af[4], bf[4];
    #pragma unroll
    for (int i = 0; i < 4; ++i) {
      af[i] = *(const short8*)(sA + (wm * 64 + i * 16 + fr) * BK + fq);
      bf[i] = *(const short8*)(sB + (wn * 64 + i * 16 + fr) * BK + fq);
    }
    #pragma unroll
    for (int i = 0; i < 4; ++i)
      #pragma unroll
      for (int j = 0; j < 4; ++j)
        acc[i][j] = __builtin_amdgcn_mfma_f32_16x16x32_bf16(af[i], bf[j], acc[i][j], 0, 0, 0);
    __syncthreads();
  }

  // epilogue: C/D layout col=lane&15, row=(lane>>4)*4+reg  [m89/m91-verified]
  const int nrm = *nrmflag;
  const int cq  = lane >> 4;   // 0..3
  const int cc  = lane & 15;

  float ibv[4];
  #pragma unroll
  for (int j = 0; j < 4; ++j) ibv[j] = ib[rowB0 + wn * 64 + j * 16 + cc];

  #pragma unroll
  for (int i = 0; i < 4; ++i) {
    #pragma unroll
    for (int r = 0; r < 4; ++r) {
      const size_t row = rowA0 + wm * 64 + i * 16 + cq * 4 + r;
      const float iav  = ia[row];
      float* crow = C + row * (size_t)M + rowB0 + wn * 64 + cc;
      #pragma unroll
      for (int j = 0; j < 4; ++j) {
        float v = acc[i][j][r];
        if (nrm) v *= iav * ibv[j];      // ~= v / (sqrt(n1*n2)+eps), err ~2.5e-7
        crow[j * 16] = v;
      }
    }
  }
}

// ---------------- correctness fallback (fp32, used only if ws too small) ----
__global__ __launch_bounds__(256) void fb_gemm(
    const float* __restrict__ A, const float* __restrict__ B,
    const float* __restrict__ ia, const float* __restrict__ ib,
    const int* __restrict__ nrmflag, float* __restrict__ C, int N, int M) {
  __shared__ float sA[32][33];
  __shared__ float sB[32][33];
  const int tx = threadIdx.x & 31;
  const int ty = threadIdx.x >> 5;   // 0..7
  const size_t row0 = (size_t)blockIdx.y * 32;
  const size_t col0 = (size_t)blockIdx.x * 32;
  float acc[4] = {0.f, 0.f, 0.f, 0.f};
  for (int k0 = 0; k0 < D; k0 += 32) {
    #pragma unroll
    for (int r = 0; r < 4; ++r) {
      sA[ty + 8 * r][tx] = A[(row0 + ty + 8 * r) * D + k0 + tx];
      sB[ty + 8 * r][tx] = B[(col0 + ty + 8 * r) * D + k0 + tx];
    }
    __syncthreads();
    #pragma unroll 8
    for (int kk = 0; kk < 32; ++kk) {
      const float bv = sB[tx][kk];
      #pragma unroll
      for (int r = 0; r < 4; ++r) acc[r] += sA[ty + 8 * r][kk] * bv;
    }
    __syncthreads();
  }
  const int nrm  = *nrmflag;
  const float iv = ib[col0 + tx];
  #pragma unroll
  for (int r = 0; r < 4; ++r) {
    const size_t row = row0 + ty + 8 * r;
    float v = acc[r];
    if (nrm) {
      const float denom = 1.0f / (ia[row] * iv) + EPS;  // sqrt(n1*n2)+eps
      v /= denom;
    }
    C[row * (size_t)M + col0 + tx] = v;
  }
}

extern "C" void kernel_launch(void* const* d_in, const int* in_sizes, int n_in,
                              void* d_out, int out_size, void* d_ws, size_t ws_size,
                              hipStream_t stream) {
  const float* A   = (const float*)d_in[0];
  const float* B   = (const float*)d_in[1];
  const int*   nrm = (const int*)d_in[2];
  float*       C   = (float*)d_out;
  const int N = in_sizes[0] / D;
  const int M = in_sizes[1] / D;

  // workspace layout: [ iaN (N f32) | ibN (M f32) | A_bf16 (N*D) | B_bf16 (M*D) ]
  float* iaN = (float*)d_ws;
  float* ibN = iaN + N;
  __hip_bfloat16* Abf = (__hip_bfloat16*)(ibN + M);
  __hip_bfloat16* Bbf = Abf + (size_t)N * D;

  const size_t need = (size_t)(N + M) * sizeof(float)
                    + (size_t)(N + M) * D * sizeof(__hip_bfloat16);
  const bool fast = (ws_size >= need) && (N % BM == 0) && (M % BN == 0);

  prep_kernel<<<N, 256, 0, stream>>>(A, fast ? Abf : nullptr, iaN);
  prep_kernel<<<M, 256, 0, stream>>>(B, fast ? Bbf : nullptr, ibN);

  if (fast) {
    gemm_bt_kernel<<<dim3(N / BM, M / BN), 256, 0, stream>>>(Abf, Bbf, iaN, ibN, nrm, C, N, M);
  } else {
    fb_gemm<<<dim3(M / 32, N / 32), 256, 0, stream>>>(A, B, iaN, ibN, nrm, C, N, M);
  }
}

// Round 3
// 346.425 us; speedup vs baseline: 1.0282x; 1.0282x over previous
//
#include <hip/hip_runtime.h>
#include <hip/hip_bf16.h>
#include <math.h>

#define EPS 1e-6f

constexpr int D  = 512;
constexpr int BM = 128;
constexpr int BN = 128;

typedef __attribute__((ext_vector_type(8))) short  short8;
typedef __attribute__((ext_vector_type(4))) float  floatx4;

__device__ inline unsigned short f2bf(float f) {
  union { __hip_bfloat16 h; unsigned short u; } cvt;
  cvt.h = __float2bfloat16(f);
  return cvt.u;
}

// ---------------- prep: fp32 -> bf16 + per-row ||x||^(-1/2) ----------------
// One wave per row. lane reads 2x float4 (cols 4L..4L+3 and 256+4L..+3),
// writes 2x ushort4 (8B packed bf16, fully coalesced), wave shuffle-reduce.
__global__ __launch_bounds__(256) void prep_kernel(
    const float* __restrict__ src, __hip_bfloat16* __restrict__ dst,
    float* __restrict__ isn, int nrows) {
  const int lane = threadIdx.x & 63;
  const int row  = blockIdx.x * 4 + (threadIdx.x >> 6);
  if (row >= nrows) return;

  const float4* p4 = (const float4*)(src + (size_t)row * D);
  const float4 v1 = p4[lane];
  const float4 v2 = p4[lane + 64];

  if (dst != nullptr) {
    ushort4 u1, u2;
    u1.x = f2bf(v1.x); u1.y = f2bf(v1.y); u1.z = f2bf(v1.z); u1.w = f2bf(v1.w);
    u2.x = f2bf(v2.x); u2.y = f2bf(v2.y); u2.z = f2bf(v2.z); u2.w = f2bf(v2.w);
    ushort4* drow = (ushort4*)(dst + (size_t)row * D);
    drow[lane]      = u1;
    drow[lane + 64] = u2;
  }

  float ss = v1.x * v1.x + v1.y * v1.y + v1.z * v1.z + v1.w * v1.w
           + v2.x * v2.x + v2.y * v2.y + v2.z * v2.z + v2.w * v2.w;
  #pragma unroll
  for (int o = 32; o > 0; o >>= 1) ss += __shfl_down(ss, o);
  if (lane == 0) {
    const float n1 = sqrtf(ss);          // ||row||
    isn[row] = 1.0f / sqrtf(n1);         // ||row||^(-1/2)
  }
}

// ---------------- main bf16 MFMA GEMM, C = A * B^T ----------
// 128x128 block tile. Logical BK=64 staged as two BK=32 sub-tiles per
// barrier pair (halves barrier count vs m97: 8 iters, 16 barriers).
// 4 waves in 2x2 (64x64 each), 4x4 of 16x16x32 MFMA per k-half.
__global__ __launch_bounds__(256) void gemm_bt_kernel(
    const __hip_bfloat16* __restrict__ A, const __hip_bfloat16* __restrict__ B,
    const float* __restrict__ ia, const float* __restrict__ ib,
    const int* __restrict__ nrmflag, float* __restrict__ C,
    int N, int M) {
  __shared__ __align__(16) __hip_bfloat16 sA[2][BM * 32];   // 16 KiB
  __shared__ __align__(16) __hip_bfloat16 sB[2][BN * 32];   // 16 KiB

  const int t    = threadIdx.x;
  const int w    = t >> 6;
  const int lane = t & 63;
  const int wm   = w & 1;        // wave row (0..1)
  const int wn   = w >> 1;       // wave col (0..1)

  const size_t rowA0 = (size_t)blockIdx.x * BM;
  const size_t rowB0 = (size_t)blockIdx.y * BN;

  floatx4 acc[4][4];
  #pragma unroll
  for (int i = 0; i < 4; ++i)
    #pragma unroll
    for (int j = 0; j < 4; ++j) acc[i][j] = (floatx4){0.f, 0.f, 0.f, 0.f};

  // staging: one wave instr = 1 KiB = 16 rows x 64B. lane -> row lane/4,
  // 16B piece (lane%4) of the 64B (=32 bf16) row chunk.
  const int ldRow = lane >> 2;           // 0..15
  const int ldCol = (lane & 3) * 8;      // bf16: 0,8,16,24
  // fragment geometry: A[m=lane&15][k=(lane>>4)*8 + j]
  const int fr = lane & 15;
  const int fq = (lane >> 4) * 8;

  const __hip_bfloat16* gA0 = A + (rowA0 + (size_t)ldRow) * D + ldCol;
  const __hip_bfloat16* gB0 = B + (rowB0 + (size_t)ldRow) * D + ldCol;

  for (int k0 = 0; k0 < D; k0 += 64) {
    #pragma unroll
    for (int h = 0; h < 2; ++h) {
      const int kc = k0 + h * 32;
      #pragma unroll
      for (int j = 0; j < 2; ++j) {
        const int c = w * 2 + j;           // chunk 0..7, wave-uniform
        __builtin_amdgcn_global_load_lds(
            (const __attribute__((address_space(1))) void*)(gA0 + (size_t)(c * 16) * D + kc),
            (__attribute__((address_space(3))) void*)(&sA[h][c * 512]), 16, 0, 0);
        __builtin_amdgcn_global_load_lds(
            (const __attribute__((address_space(1))) void*)(gB0 + (size_t)(c * 16) * D + kc),
            (__attribute__((address_space(3))) void*)(&sB[h][c * 512]), 16, 0, 0);
      }
    }
    __syncthreads();   // drains vmcnt(0): both k-half tiles visible

    #pragma unroll
    for (int h = 0; h < 2; ++h) {
      short8 af[4], bf[4];
      #pragma unroll
      for (int i = 0; i < 4; ++i) {
        af[i] = *(const short8*)(&sA[h][(wm * 64 + i * 16 + fr) * 32 + fq]);
        bf[i] = *(const short8*)(&sB[h][(wn * 64 + i * 16 + fr) * 32 + fq]);
      }
      #pragma unroll
      for (int i = 0; i < 4; ++i)
        #pragma unroll
        for (int j = 0; j < 4; ++j)
          acc[i][j] = __builtin_amdgcn_mfma_f32_16x16x32_bf16(af[i], bf[j], acc[i][j], 0, 0, 0);
    }
    __syncthreads();
  }

  // epilogue: C/D layout col=lane&15, row=(lane>>4)*4+reg  [m89/m91-verified]
  const int nrm = *nrmflag;
  const int cq  = lane >> 4;   // 0..3
  const int cc  = lane & 15;

  float ibv[4];
  #pragma unroll
  for (int j = 0; j < 4; ++j)
    ibv[j] = nrm ? ib[rowB0 + wn * 64 + j * 16 + cc] : 1.0f;

  #pragma unroll
  for (int i = 0; i < 4; ++i) {
    const size_t rbase = rowA0 + wm * 64 + i * 16 + cq * 4;
    float4 iav4 = nrm ? *(const float4*)(ia + rbase) : (float4){1.f, 1.f, 1.f, 1.f};
    const float iavr[4] = {iav4.x, iav4.y, iav4.z, iav4.w};
    #pragma unroll
    for (int r = 0; r < 4; ++r) {
      const size_t row = rbase + r;
      float* crow = C + row * (size_t)M + rowB0 + wn * 64 + cc;
      #pragma unroll
      for (int j = 0; j < 4; ++j)
        crow[j * 16] = acc[i][j][r] * iavr[r] * ibv[j];
    }
  }
}

// ---------------- correctness fallback (fp32, used only if ws too small) ----
__global__ __launch_bounds__(256) void fb_gemm(
    const float* __restrict__ A, const float* __restrict__ B,
    const float* __restrict__ ia, const float* __restrict__ ib,
    const int* __restrict__ nrmflag, float* __restrict__ C, int N, int M) {
  __shared__ float sA[32][33];
  __shared__ float sB[32][33];
  const int tx = threadIdx.x & 31;
  const int ty = threadIdx.x >> 5;   // 0..7
  const size_t row0 = (size_t)blockIdx.y * 32;
  const size_t col0 = (size_t)blockIdx.x * 32;
  float acc[4] = {0.f, 0.f, 0.f, 0.f};
  for (int k0 = 0; k0 < D; k0 += 32) {
    #pragma unroll
    for (int r = 0; r < 4; ++r) {
      sA[ty + 8 * r][tx] = A[(row0 + ty + 8 * r) * D + k0 + tx];
      sB[ty + 8 * r][tx] = B[(col0 + ty + 8 * r) * D + k0 + tx];
    }
    __syncthreads();
    #pragma unroll 8
    for (int kk = 0; kk < 32; ++kk) {
      const float bv = sB[tx][kk];
      #pragma unroll
      for (int r = 0; r < 4; ++r) acc[r] += sA[ty + 8 * r][kk] * bv;
    }
    __syncthreads();
  }
  const int nrm  = *nrmflag;
  const float iv = ib[col0 + tx];
  #pragma unroll
  for (int r = 0; r < 4; ++r) {
    const size_t row = row0 + ty + 8 * r;
    float v = acc[r];
    if (nrm) {
      const float denom = 1.0f / (ia[row] * iv) + EPS;  // sqrt(n1*n2)+eps
      v /= denom;
    }
    C[row * (size_t)M + col0 + tx] = v;
  }
}

extern "C" void kernel_launch(void* const* d_in, const int* in_sizes, int n_in,
                              void* d_out, int out_size, void* d_ws, size_t ws_size,
                              hipStream_t stream) {
  const float* A   = (const float*)d_in[0];
  const float* B   = (const float*)d_in[1];
  const int*   nrm = (const int*)d_in[2];
  float*       C   = (float*)d_out;
  const int N = in_sizes[0] / D;
  const int M = in_sizes[1] / D;

  // workspace layout: [ iaN (N f32) | ibN (M f32) | A_bf16 (N*D) | B_bf16 (M*D) ]
  float* iaN = (float*)d_ws;
  float* ibN = iaN + N;
  __hip_bfloat16* Abf = (__hip_bfloat16*)(ibN + M);
  __hip_bfloat16* Bbf = Abf + (size_t)N * D;

  const size_t need = (size_t)(N + M) * sizeof(float)
                    + (size_t)(N + M) * D * sizeof(__hip_bfloat16);
  const bool fast = (ws_size >= need) && (N % BM == 0) && (M % BN == 0);

  prep_kernel<<<(N + 3) / 4, 256, 0, stream>>>(A, fast ? Abf : nullptr, iaN, N);
  prep_kernel<<<(M + 3) / 4, 256, 0, stream>>>(B, fast ? Bbf : nullptr, ibN, M);

  if (fast) {
    gemm_bt_kernel<<<dim3(N / BM, M / BN), 256, 0, stream>>>(Abf, Bbf, iaN, ibN, nrm, C, N, M);
  } else {
    fb_gemm<<<dim3(M / 32, N / 32), 256, 0, stream>>>(A, B, iaN, ibN, nrm, C, N, M);
  }
}